// Round 1
// baseline (594.062 us; speedup 1.0000x reference)
//
#include <hip/hip_runtime.h>
#include <math.h>

#define B_SZ 512
#define IN_F 342
#define HID  512
#define OUT_F 311

// ---------------------------------------------------------------------------
// prep: per-sample Catmull-Rom coefficients a[b][4] and expanded layer-0 input
//   A0[b, k*IN_F + i] = a[b,k] * x[b,i]      (512 x 1368)
// ---------------------------------------------------------------------------
__global__ __launch_bounds__(256) void prep_kernel(const float* __restrict__ p,
                                                   const float* __restrict__ x,
                                                   float* __restrict__ coef,
                                                   float* __restrict__ A0) {
  int b = blockIdx.x;
  __shared__ float cf[4];
  if (threadIdx.x == 0) {
    float p4 = p[b] * 4.0f;
    float mu = p4 - floorf(p4);          // jnp.mod(p4, 1.0)
    int i1 = ((int)p4) & 3;              // p4 in [0,4)
    float mu2 = mu * mu, mu3 = mu2 * mu;
    float c0 = -0.5f * mu3 + mu2 - 0.5f * mu;            // weight of W[i0]
    float c1 =  1.5f * mu3 - 2.5f * mu2 + 1.0f;          // weight of W[i1]
    float c2 = -1.5f * mu3 + 2.0f * mu2 + 0.5f * mu;     // weight of W[i2]
    float c3 =  0.5f * mu3 - 0.5f * mu2;                 // weight of W[i3]
    cf[(i1 + 3) & 3] = c0;   // i0 = (i1-1) mod 4
    cf[i1]           = c1;
    cf[(i1 + 1) & 3] = c2;
    cf[(i1 + 2) & 3] = c3;
  }
  __syncthreads();
  if (threadIdx.x < 4) coef[b * 4 + threadIdx.x] = cf[threadIdx.x];
  float c0 = cf[0], c1 = cf[1], c2 = cf[2], c3 = cf[3];
  const float* xr = x + (size_t)b * IN_F;
  float* dst = A0 + (size_t)b * (4 * IN_F);
  for (int i = threadIdx.x; i < IN_F; i += 256) {
    float xv = xr[i];
    dst[i]            = c0 * xv;
    dst[IN_F + i]     = c1 * xv;
    dst[2 * IN_F + i] = c2 * xv;
    dst[3 * IN_F + i] = c3 * xv;
  }
}

// ---------------------------------------------------------------------------
// Tiled fp32 GEMM:  out_pre = A(MxK) @ W(KxN) + bias_interp
//   bias_interp[b,n] = sum_k coef[b,k]*bias[k,n]
//   ACT: apply ELU. EXPAND: write 4 scaled copies (next layer's A, row len 4N)
// 64x64 tile, 256 threads, 4x4 micro-tile, BK=16.
// ---------------------------------------------------------------------------
template <int ACT, int EXPAND>
__global__ __launch_bounds__(256) void gemm_kernel(
    const float* __restrict__ A,     // M x K
    const float* __restrict__ W,     // K x N
    const float* __restrict__ bias,  // 4 x N
    const float* __restrict__ coef,  // M x 4
    float* __restrict__ out,         // EXPAND ? M x 4N : M x N
    int M, int N, int K) {
  constexpr int BM = 64, BN = 64, BK = 16;
  __shared__ float As[BK][BM];  // stride 64 floats: f4 reads conflict-free
  __shared__ float Bs[BK][BN];

  const int tid = threadIdx.x;
  const int tx = tid & 15;   // 0..15 -> output cols tx*4..+3
  const int ty = tid >> 4;   // 0..15 -> output rows ty*4..+3
  const int m0 = blockIdx.y * BM;
  const int n0 = blockIdx.x * BN;

  const int arow = tid >> 2;         // 0..63
  const int acol = (tid & 3) * 4;    // 0,4,8,12
  const int brow = tid >> 4;         // 0..15
  const int bcol = (tid & 15) * 4;   // 0..60

  float acc[4][4] = {};

  for (int kt = 0; kt < K; kt += BK) {
    // A tile (BM x BK) -> transposed store As[k][m]
    {
      const float* ap = A + (size_t)(m0 + arow) * K + kt + acol;
#pragma unroll
      for (int j = 0; j < 4; ++j) {
        float v = (kt + acol + j < K) ? ap[j] : 0.0f;
        As[acol + j][arow] = v;
      }
    }
    // B tile (BK x BN)
    {
      int gk = kt + brow;
      const float* wp = W + (size_t)gk * N + n0 + bcol;
#pragma unroll
      for (int j = 0; j < 4; ++j) {
        float v = (gk < K && (n0 + bcol + j) < N) ? wp[j] : 0.0f;
        Bs[brow][bcol + j] = v;
      }
    }
    __syncthreads();
#pragma unroll
    for (int kk = 0; kk < BK; ++kk) {
      float4 av = *reinterpret_cast<const float4*>(&As[kk][ty * 4]);
      float4 bv = *reinterpret_cast<const float4*>(&Bs[kk][tx * 4]);
      float a_[4] = {av.x, av.y, av.z, av.w};
      float b_[4] = {bv.x, bv.y, bv.z, bv.w};
#pragma unroll
      for (int r = 0; r < 4; ++r)
#pragma unroll
        for (int c = 0; c < 4; ++c) acc[r][c] += a_[r] * b_[c];
    }
    __syncthreads();
  }

  // epilogue: bias interp + ELU + (expand | store)
#pragma unroll
  for (int r = 0; r < 4; ++r) {
    int gm = m0 + ty * 4 + r;
    float cf0 = coef[gm * 4 + 0];
    float cf1 = coef[gm * 4 + 1];
    float cf2 = coef[gm * 4 + 2];
    float cf3 = coef[gm * 4 + 3];
#pragma unroll
    for (int c = 0; c < 4; ++c) {
      int gn = n0 + tx * 4 + c;
      if (gn < N) {
        float bi = cf0 * bias[gn] + cf1 * bias[N + gn] + cf2 * bias[2 * N + gn] +
                   cf3 * bias[3 * N + gn];
        float v = acc[r][c] + bi;
        if (ACT) v = (v > 0.0f) ? v : expm1f(v);
        if (EXPAND) {
          float* dst = out + (size_t)gm * (4 * N) + gn;
          dst[0]     = cf0 * v;
          dst[N]     = cf1 * v;
          dst[2 * N] = cf2 * v;
          dst[3 * N] = cf3 * v;
        } else {
          out[(size_t)gm * N + gn] = v;
        }
      }
    }
  }
}

extern "C" void kernel_launch(void* const* d_in, const int* in_sizes, int n_in,
                              void* d_out, int out_size, void* d_ws, size_t ws_size,
                              hipStream_t stream) {
  const float* p  = (const float*)d_in[0];
  const float* x  = (const float*)d_in[1];
  const float* W0 = (const float*)d_in[2];
  const float* b0 = (const float*)d_in[3];
  const float* W1 = (const float*)d_in[4];
  const float* b1 = (const float*)d_in[5];
  const float* W2 = (const float*)d_in[6];
  const float* b2 = (const float*)d_in[7];
  float* out = (float*)d_out;

  float* ws   = (float*)d_ws;
  float* coef = ws;                        // 512*4
  float* A0   = coef + B_SZ * 4;           // 512*1368
  float* A1   = A0 + (size_t)B_SZ * 4 * IN_F;  // 512*2048
  float* A2   = A1 + (size_t)B_SZ * 4 * HID;   // 512*2048

  prep_kernel<<<B_SZ, 256, 0, stream>>>(p, x, coef, A0);

  // Layer 0: (512 x 1368) @ (1368 x 512) -> expanded A1 (512 x 2048)
  gemm_kernel<1, 1><<<dim3(HID / 64, B_SZ / 64), 256, 0, stream>>>(
      A0, W0, b0, coef, A1, B_SZ, HID, 4 * IN_F);
  // Layer 1: (512 x 2048) @ (2048 x 512) -> expanded A2 (512 x 2048)
  gemm_kernel<1, 1><<<dim3(HID / 64, B_SZ / 64), 256, 0, stream>>>(
      A1, W1, b1, coef, A2, B_SZ, HID, 4 * HID);
  // Layer 2: (512 x 2048) @ (2048 x 311) -> out (512 x 311)
  gemm_kernel<0, 0><<<dim3((OUT_F + 63) / 64, B_SZ / 64), 256, 0, stream>>>(
      A2, W2, b2, coef, out, B_SZ, OUT_F, 4 * HID);
}

// Round 2
// 118.267 us; speedup vs baseline: 5.0230x; 5.0230x over previous
//
#include <hip/hip_runtime.h>
#include <math.h>

typedef __bf16 bf16x8 __attribute__((ext_vector_type(8)));
typedef __bf16 bf16x4 __attribute__((ext_vector_type(4)));
typedef float f32x4 __attribute__((ext_vector_type(4)));

#define B_SZ 512
#define IN_F 342
#define HID  512
#define OUT_F 311

// ---------------------------------------------------------------------------
// prep: per-sample Catmull-Rom coefficients coef[b][4] and expanded layer-0
// input in bf16:  A0[b, k*IN_F + i] = coef[b,k] * x[b,i]   (512 x 1368 bf16)
// ---------------------------------------------------------------------------
__global__ __launch_bounds__(256) void prep_kernel(const float* __restrict__ p,
                                                   const float* __restrict__ x,
                                                   float* __restrict__ coef,
                                                   __bf16* __restrict__ A0) {
  int b = blockIdx.x;
  __shared__ float cf[4];
  if (threadIdx.x == 0) {
    float p4 = p[b] * 4.0f;
    float mu = p4 - floorf(p4);
    int i1 = ((int)p4) & 3;
    float mu2 = mu * mu, mu3 = mu2 * mu;
    float c0 = -0.5f * mu3 + mu2 - 0.5f * mu;
    float c1 =  1.5f * mu3 - 2.5f * mu2 + 1.0f;
    float c2 = -1.5f * mu3 + 2.0f * mu2 + 0.5f * mu;
    float c3 =  0.5f * mu3 - 0.5f * mu2;
    cf[(i1 + 3) & 3] = c0;
    cf[i1]           = c1;
    cf[(i1 + 1) & 3] = c2;
    cf[(i1 + 2) & 3] = c3;
  }
  __syncthreads();
  if (threadIdx.x < 4) coef[b * 4 + threadIdx.x] = cf[threadIdx.x];
  float c0 = cf[0], c1 = cf[1], c2 = cf[2], c3 = cf[3];
  const float* xr = x + (size_t)b * IN_F;
  __bf16* dst = A0 + (size_t)b * (4 * IN_F);
  for (int i = threadIdx.x; i < IN_F; i += 256) {
    float xv = xr[i];
    dst[i]            = (__bf16)(c0 * xv);
    dst[IN_F + i]     = (__bf16)(c1 * xv);
    dst[2 * IN_F + i] = (__bf16)(c2 * xv);
    dst[3 * IN_F + i] = (__bf16)(c3 * xv);
  }
}

// ---------------------------------------------------------------------------
// bf16 MFMA GEMM: out = A(MxK bf16) @ W(KxN fp32->bf16) + bias_interp
// 64x64 tile, BK=64, 256 threads = 4 waves (2x2), wave tile 32x32 (2x2 frags
// of 16x16x32). LDS rows padded to 72 elems (144B) for bank spread + b128
// alignment. W transposed to [n][k] during staging (B-frag wants k-contig).
// Next-tile global loads issued into regs before compute (latency hiding).
// ---------------------------------------------------------------------------
template <int ACT, int EXPAND, int NVEC>
__global__ __launch_bounds__(256) void gemm_mfma(
    const __bf16* __restrict__ A,   // M x K (bf16, row-major)
    const float* __restrict__ W,    // K x N (fp32, row-major)
    const float* __restrict__ bias, // 4 x N
    const float* __restrict__ coef, // M x 4
    void* __restrict__ outv,        // EXPAND ? bf16 M x 4N : float M x N
    int M, int N, int K) {
  constexpr int BK = 64;
  constexpr int LDT = 72;  // LDS row stride (elements)
  __shared__ __bf16 Als[64 * LDT];
  __shared__ __bf16 Bls[64 * LDT];

  const int tid = threadIdx.x;
  const int l = tid & 63;
  const int wave = tid >> 6;
  const int wm = wave >> 1, wn = wave & 1;
  const int lr = l & 15, lk = l >> 4;
  const int m0 = blockIdx.y * 64;
  const int n0 = blockIdx.x * 64;

  // A staging: thread -> (row ar, octets aoct0, aoct0+1)
  const int ar = tid >> 2;
  const int aoct0 = (tid & 3) * 2;
  // B staging: thread -> 4x4 block at (k = kb*4.., n = nb*4..)
  const int kb = tid >> 4;
  const int nb = tid & 15;

  f32x4 acc[2][2] = {};
  bf16x8 areg[2];
  float wreg[4][4];

  const int KT = (K + BK - 1) / BK;

  auto loadA = [&](int kt) {
#pragma unroll
    for (int r = 0; r < 2; ++r) {
      int gk = kt + (aoct0 + r) * 8;  // K % 8 == 0: octets never partial
      if (gk < K)
        areg[r] = *(const bf16x8*)&A[(size_t)(m0 + ar) * K + gk];
      else
        areg[r] = bf16x8{};
    }
  };

  auto loadB = [&](int kt) {
    const int n = n0 + nb * 4;
#pragma unroll
    for (int r = 0; r < 4; ++r) {
      int gk = kt + kb * 4 + r;
      if (NVEC) {
        if (gk < K)
          *(f32x4*)wreg[r] = *(const f32x4*)&W[(size_t)gk * N + n];
        else
          *(f32x4*)wreg[r] = f32x4{};
      } else {
#pragma unroll
        for (int j = 0; j < 4; ++j)
          wreg[r][j] = (gk < K && n + j < N) ? W[(size_t)gk * N + n + j] : 0.0f;
      }
    }
  };

  auto storeLDS = [&]() {
#pragma unroll
    for (int r = 0; r < 2; ++r)
      *(bf16x8*)&Als[ar * LDT + (aoct0 + r) * 8] = areg[r];
#pragma unroll
    for (int j = 0; j < 4; ++j) {
      bf16x4 v = {(__bf16)wreg[0][j], (__bf16)wreg[1][j],
                  (__bf16)wreg[2][j], (__bf16)wreg[3][j]};
      *(bf16x4*)&Bls[(nb * 4 + j) * LDT + kb * 4] = v;  // B^T: [n][k]
    }
  };

  auto compute = [&]() {
#pragma unroll
    for (int kk = 0; kk < BK; kk += 32) {
      bf16x8 af[2], bg[2];
#pragma unroll
      for (int i = 0; i < 2; ++i) {
        af[i] = *(const bf16x8*)&Als[(wm * 32 + i * 16 + lr) * LDT + kk + lk * 8];
        bg[i] = *(const bf16x8*)&Bls[(wn * 32 + i * 16 + lr) * LDT + kk + lk * 8];
      }
#pragma unroll
      for (int i = 0; i < 2; ++i)
#pragma unroll
        for (int j = 0; j < 2; ++j)
          acc[i][j] = __builtin_amdgcn_mfma_f32_16x16x32_bf16(af[i], bg[j],
                                                              acc[i][j], 0, 0, 0);
    }
  };

  loadA(0);
  loadB(0);
  for (int t = 0; t < KT; ++t) {
    __syncthreads();  // previous compute's LDS reads done
    storeLDS();
    __syncthreads();
    if (t + 1 < KT) {  // issue next tile's global loads before MFMA phase
      loadA((t + 1) * BK);
      loadB((t + 1) * BK);
    }
    compute();
  }

  // epilogue: bias interp + ELU + (expand | store)
  // C/D layout: col = lane&15, row = (lane>>4)*4 + reg   [measured m89]
#pragma unroll
  for (int fn = 0; fn < 2; ++fn) {
    int gn = n0 + wn * 32 + fn * 16 + lr;
    if (NVEC || gn < N) {
      float b0 = bias[gn], b1 = bias[N + gn], b2 = bias[2 * N + gn],
            b3 = bias[3 * N + gn];
#pragma unroll
      for (int fm = 0; fm < 2; ++fm) {
        int gmb = m0 + wm * 32 + fm * 16 + lk * 4;
#pragma unroll
        for (int r = 0; r < 4; ++r) {
          int gm = gmb + r;
          f32x4 cf = *(const f32x4*)&coef[gm * 4];
          float v = acc[fm][fn][r] + cf[0] * b0 + cf[1] * b1 + cf[2] * b2 + cf[3] * b3;
          if (ACT) v = (v > 0.0f) ? v : expm1f(v);
          if (EXPAND) {
            __bf16* dst = (__bf16*)outv + (size_t)gm * (4 * N) + gn;
            dst[0]     = (__bf16)(cf[0] * v);
            dst[N]     = (__bf16)(cf[1] * v);
            dst[2 * N] = (__bf16)(cf[2] * v);
            dst[3 * N] = (__bf16)(cf[3] * v);
          } else {
            ((float*)outv)[(size_t)gm * N + gn] = v;
          }
        }
      }
    }
  }
}

extern "C" void kernel_launch(void* const* d_in, const int* in_sizes, int n_in,
                              void* d_out, int out_size, void* d_ws, size_t ws_size,
                              hipStream_t stream) {
  const float* p  = (const float*)d_in[0];
  const float* x  = (const float*)d_in[1];
  const float* W0 = (const float*)d_in[2];
  const float* b0 = (const float*)d_in[3];
  const float* W1 = (const float*)d_in[4];
  const float* b1 = (const float*)d_in[5];
  const float* W2 = (const float*)d_in[6];
  const float* b2 = (const float*)d_in[7];
  float* out = (float*)d_out;

  char* wsb = (char*)d_ws;
  float* coef = (float*)wsb;                                   // 8 KB
  __bf16* A0 = (__bf16*)(wsb + 8192);                          // 512x1368
  __bf16* A1 = (__bf16*)(wsb + 8192 + (size_t)B_SZ * 4 * IN_F * 2);
  __bf16* A2 = A1 + (size_t)B_SZ * 4 * HID;                    // 512x2048

  prep_kernel<<<B_SZ, 256, 0, stream>>>(p, x, coef, A0);

  // L0: (512 x 1368) @ (1368 x 512) -> ELU -> expand -> A1 (bf16 512x2048)
  gemm_mfma<1, 1, 1><<<dim3(8, 8), 256, 0, stream>>>(
      A0, W0, b0, coef, A1, B_SZ, HID, 4 * IN_F);
  // L1: (512 x 2048) @ (2048 x 512) -> ELU -> expand -> A2 (bf16 512x2048)
  gemm_mfma<1, 1, 1><<<dim3(8, 8), 256, 0, stream>>>(
      A1, W1, b1, coef, A2, B_SZ, HID, 4 * HID);
  // L2: (512 x 2048) @ (2048 x 311) -> out (fp32)
  gemm_mfma<0, 0, 0><<<dim3((OUT_F + 63) / 64, 8), 256, 0, stream>>>(
      A2, W2, b2, coef, out, B_SZ, OUT_F, 4 * HID);
}